// Round 9
// baseline (468.603 us; speedup 1.0000x reference)
//
#include <hip/hip_runtime.h>
#include <cstdint>
#include <math.h>

// MoE top-2 of 16 experts. N=131072, D=512, H=128, E=16, O=512.  All-fp16 path:
//   kconv (Wg1->W1 f16 [H][D], Wg2->frag-order f16, CTRL zero; 17 blocks)
//   -> kgate (128 tok/block fp16 MFMA gating + x-f16 store + pair histogram;
//             tail converts one We tile -> Wt f16 [O][D] per block)
//   -> krefine (fp64 exact gating for flagged tokens; patches counts)
//   -> kscatter (fused block-local scan + scatter; block 0 writes bases/tile list)
//   -> kexpert3 (pair-bucket f16 GEMM, 256 tok x 128 cols, BK=32, per-wave 64x64
//      (acc=64 regs -> 4 waves/SIMD), triple-buffered LDS (75KB -> 2 blocks/CU),
//      counted vmcnt(3); gate-A folded into accumulator; single store)

#define NTOK 131072
#define DDIM 512

typedef _Float16 f16;
typedef f16   f16x8 __attribute__((ext_vector_type(8)));
typedef float f32x4 __attribute__((ext_vector_type(4)));

__device__ __forceinline__ void load_lds16(const void* g, void* l){
  __builtin_amdgcn_global_load_lds(
      (const __attribute__((address_space(1))) void*)(uintptr_t)g,
      (__attribute__((address_space(3))) void*)(uintptr_t)l, 16, 0, 0);
}

__device__ __forceinline__ f32x4 MFMAH(f16x8 a, f16x8 b, f32x4 c){
  return __builtin_amdgcn_mfma_f32_16x16x32_f16(a, b, c, 0, 0, 0);
}

// ---- swizzled LDS helpers -----------------------------------------------------
// 64-col f16 tile (pitch 128B): logical (row r, 16B chunk q) at r*128+((q^(r&7))<<4)
__device__ __forceinline__ f16x8 readF64h(const char* buf, int r, int q){
  return *(const f16x8*)(buf + r*128 + ((q ^ (r & 7)) << 4));
}
// 32-col f16 tile (pitch 64B), 4 chunks/row
__device__ __forceinline__ f16x8 readF32h(const char* buf, int r, int q){
  return *(const f16x8*)(buf + r*64 + ((q ^ (r & 3)) << 4));
}
__device__ __forceinline__ f16x8 pack8f(const float* fv){
  f16x8 v;
  #pragma unroll
  for (int j=0;j<8;++j) v[j] = (f16)fv[j];   // RNE v_cvt_f16_f32
  return v;
}

// ---- kconv: Wg1 [D][H] f32 -> W1 f16 [H][D]; Wg2 -> frag-order f16; CTRL zero.
__global__ void kconv(const float* __restrict__ Wg1, const float* __restrict__ Wg2,
                      f16* __restrict__ W1, char* __restrict__ Wg2f, int* __restrict__ ctrl){
  __shared__ float sh[64*65];
  int bx = blockIdx.x, tid = threadIdx.x;
  if (bx < 16){
    int dt = bx >> 1, ht = bx & 1;
    const float* src = Wg1 + (size_t)dt*64*128 + ht*64;
    #pragma unroll
    for (int it=0; it<16; ++it){ int idx = it*256+tid; int dl = idx>>6, ol = idx&63;
      sh[dl*65+ol] = src[dl*128+ol]; }
    __syncthreads();
    #pragma unroll
    for (int it=0; it<16; ++it){ int idx = it*256+tid; int ol = idx>>6, dl = idx&63;
      W1[(size_t)(ht*64+ol)*512 + dt*64+dl] = (f16)sh[dl*65+ol]; }
  } else {
    int ks = tid >> 6, l = tid & 63;
    int col = l & 15, kb = ks*32 + ((l >> 4) << 3);
    f16x8 v;
    #pragma unroll
    for (int j=0;j<8;++j) v[j] = (f16)Wg2[(kb+j)*16 + col];
    *(f16x8*)(Wg2f + (ks*64+l)*16) = v;
    #pragma unroll
    for (int i = 0; i < 8; ++i) ctrl[tid + i*256] = 0;   // zero CTRL (8KB)
  }
}

// ---- kgate: 128 tok/block fp16 gating + x-f16 producer + pair histogram.
__global__ __launch_bounds__(256) void kgate(
    const float* __restrict__ x, const f16* __restrict__ W1, const char* __restrict__ Wg2f,
    const float* __restrict__ bg1, const float* __restrict__ bg2,
    const float* __restrict__ We, f16* __restrict__ Wt,
    f16* __restrict__ xbf,
    int2* __restrict__ gate_e, float2* __restrict__ gate_g,
    int* __restrict__ refine_cnt, int* __restrict__ refine_list, int* __restrict__ counts)
{
  __shared__ __align__(16) char sm[76800];
  const int BOFF = 32768;
  const int LOGI = 67584;
  const int HIST = 75776;
  int tid = threadIdx.x, bid = blockIdx.x;
  int lane = tid & 63, w = tid >> 6, wm = w >> 1, wn = w & 1;
  int l15 = lane & 15, l4 = lane >> 4;
  int t0 = bid * 128;
  int ar = tid >> 1, ach = tid & 1;
  const float* xrow = x + (size_t)(t0 + ar) * DDIM;
  char* xbfb = (char*)xbf;
  f32x4 acc[4][4];
  #pragma unroll
  for (int n=0;n<4;++n){
    float bb = bg1[wn*64 + n*16 + l15];
    f32x4 z = {bb, bb, bb, bb};
    #pragma unroll
    for (int m=0;m<4;++m) acc[m][n] = z;
  }
  auto stageA = [&](int ks, char* abuf){
    float fv[32];
    #pragma unroll
    for (int q=0;q<8;++q) *(float4*)&fv[q*4] = *(const float4*)(xrow + ks*64 + ach*32 + q*4);
    f16x8 h0 = pack8f(fv), h1 = pack8f(fv+8), h2 = pack8f(fv+16), h3 = pack8f(fv+24);
    *(f16x8*)(abuf + ar*128 + (((ach*4+0) ^ (ar & 7)) << 4)) = h0;
    *(f16x8*)(abuf + ar*128 + (((ach*4+1) ^ (ar & 7)) << 4)) = h1;
    *(f16x8*)(abuf + ar*128 + (((ach*4+2) ^ (ar & 7)) << 4)) = h2;
    *(f16x8*)(abuf + ar*128 + (((ach*4+3) ^ (ar & 7)) << 4)) = h3;
    if (xbf){
      char* xd = xbfb + (size_t)(t0+ar)*1024 + ks*128 + ach*64;
      *(f16x8*)xd = h0; *(f16x8*)(xd+16) = h1; *(f16x8*)(xd+32) = h2; *(f16x8*)(xd+48) = h3;
    }
  };
  auto stageB = [&](int ks, char* lds){
    const char* gb = (const char*)W1 + ks*128;
    #pragma unroll
    for (int i = 0; i < 4; ++i){
      int lin = i*4096 + tid*16;
      int r = lin >> 7, g = (lin >> 4) & 7;
      load_lds16(gb + r*1024 + ((g ^ (r & 7)) << 4), lds + i*4096 + ((tid >> 6) << 10));
    }
  };
  stageB(0, sm + BOFF); stageA(0, sm);
  for (int ks = 0; ks < 8; ++ks){
    int b = ks & 1;
    asm volatile("s_waitcnt vmcnt(0)" ::: "memory");
    __syncthreads();
    if (ks < 7) stageB(ks+1, sm + BOFF + (b^1)*16384);
    const char* Ab = sm + b*16384;
    const char* Bb = sm + BOFF + b*16384;
    f16x8 ah[4][2], bh[4][2];
    #pragma unroll
    for (int m=0;m<4;++m)
      #pragma unroll
      for (int kf=0;kf<2;++kf) ah[m][kf] = readF64h(Ab, wm*64 + m*16 + l15, kf*4 + l4);
    #pragma unroll
    for (int n=0;n<4;++n)
      #pragma unroll
      for (int kf=0;kf<2;++kf) bh[n][kf] = readF64h(Bb, wn*64 + n*16 + l15, kf*4 + l4);
    #pragma unroll
    for (int m=0;m<4;++m)
      #pragma unroll
      for (int n=0;n<4;++n){
        acc[m][n] = MFMAH(ah[m][0], bh[n][0], acc[m][n]);
        acc[m][n] = MFMAH(ah[m][1], bh[n][1], acc[m][n]);
      }
    if (ks < 7) stageA(ks+1, sm + (b^1)*16384);
  }
  __syncthreads();
  uint4 wgf[4];
  #pragma unroll
  for (int ksq=0; ksq<4; ++ksq) wgf[ksq] = *(const uint4*)(Wg2f + (ksq*64+lane)*16);
  float* hl = (float*)sm;
  #pragma unroll
  for (int m=0;m<4;++m)
    #pragma unroll
    for (int n=0;n<4;++n)
      #pragma unroll
      for (int j=0;j<4;++j){
        int row = wm*64 + m*16 + (l4 << 2) + j;
        int col = wn*64 + n*16 + l15;
        float uv = acc[m][n][j];
        hl[row*132 + col] = 0.5f * uv * (1.0f + erff(uv * 0.70710678118654752f));
      }
  __syncthreads();
  {
    float bb2 = bg2[l15];
    float* ll = (float*)(sm + LOGI);
    #pragma unroll
    for (int sub=0; sub<2; ++sub){
      f32x4 acc2 = {bb2, bb2, bb2, bb2};
      #pragma unroll
      for (int ksq=0; ksq<4; ++ksq){
        const float* hp = (const float*)sm + (w*32 + sub*16 + l15)*132 + ksq*32 + l4*8;
        f16x8 afr;
        #pragma unroll
        for (int j=0;j<8;++j) afr[j] = (f16)hp[j];
        acc2 = MFMAH(afr, *(const f16x8*)&wgf[ksq], acc2);
      }
      #pragma unroll
      for (int j=0;j<4;++j) ll[(w*32 + sub*16 + l4*4 + j)*16 + l15] = acc2[j];
    }
  }
  int* hist = (int*)(sm + HIST);
  hist[tid] = 0;
  __syncthreads();
  if (tid < 128){
    int t = t0 + tid;
    const float* l = (const float*)(sm + LOGI) + tid*16;
    float b1 = -1e30f, b2 = -1e30f, b3 = -1e30f; int e1 = 0, e2 = 0;
    #pragma unroll
    for (int e = 0; e < 16; ++e){
      float v = l[e];
      if (v > b1){ b3 = b2; b2 = b1; e2 = e1; b1 = v; e1 = e; }
      else if (v > b2){ b3 = b2; b2 = v; e2 = e; }
      else if (v > b3){ b3 = v; }
    }
    float s = 0.f;
    #pragma unroll
    for (int e = 0; e < 16; ++e) s += expf(l[e] - b1);
    float inv = 1.f / s;
    gate_e[t] = make_int2(e1, e2);
    gate_g[t] = make_float2(inv + 1e-4f, expf(b2 - b1) * inv + 1e-4f);
    if (b2 - b3 < 1e-3f){
      int pos = atomicAdd(refine_cnt, 1);
      refine_list[pos] = t;
    }
    int pa = min(e1, e2), pb = max(e1, e2);
    atomicAdd(&hist[pa*16 + pb], 1);
  }
  __syncthreads();
  if (hist[tid]) atomicAdd(&counts[tid], hist[tid]);
  // ---- tail: convert one We 64x64 tile -> Wt (fused kconv work) ----
  __syncthreads();
  {
    float* sh = (float*)sm;
    int e = bid >> 6, dt = (bid >> 3) & 7, ot = bid & 7;
    const float* src = We + (size_t)e*262144 + (size_t)dt*64*512 + ot*64;
    #pragma unroll
    for (int it=0; it<16; ++it){ int idx = it*256+tid; int dl = idx>>6, ol = idx&63;
      sh[dl*65+ol] = src[dl*512+ol]; }
    __syncthreads();
    f16* dst = Wt + (size_t)e*262144 + (size_t)ot*64*512 + dt*64;
    #pragma unroll
    for (int it=0; it<16; ++it){ int idx = it*256+tid; int ol = idx>>6, dl = idx&63;
      dst[(size_t)ol*512+dl] = (f16)sh[dl*65+ol]; }
  }
}

// ---- krefine: exact fp64 gating for flagged tokens (4-way chains); patches counts.
__global__ __launch_bounds__(128) void krefine(
    const float* __restrict__ x, const float* __restrict__ Wg1, const float* __restrict__ bg1,
    const float* __restrict__ Wg2, const float* __restrict__ bg2,
    const int* __restrict__ refine_cnt, const int* __restrict__ refine_list,
    int2* __restrict__ gate_e, float2* __restrict__ gate_g, int* __restrict__ counts)
{
  __shared__ float  xs[512];
  __shared__ double hd[128];
  __shared__ double ld[16];
  int tid = threadIdx.x;
  int rc = *refine_cnt;
  for (int i = blockIdx.x; i < rc; i += gridDim.x){
    __syncthreads();
    int t = refine_list[i];
    *(float4*)(xs + tid*4) = *(const float4*)(x + (size_t)t*DDIM + tid*4);
    __syncthreads();
    double a0=0.0, a1=0.0, a2=0.0, a3=0.0;
    for (int d = 0; d < 512; d += 4){
      a0 += (double)xs[d]   * (double)Wg1[(d)*128 + tid];
      a1 += (double)xs[d+1] * (double)Wg1[(d+1)*128 + tid];
      a2 += (double)xs[d+2] * (double)Wg1[(d+2)*128 + tid];
      a3 += (double)xs[d+3] * (double)Wg1[(d+3)*128 + tid];
    }
    double a = (double)bg1[tid] + ((a0+a1)+(a2+a3));
    hd[tid] = 0.5 * a * (1.0 + erf(a * 0.70710678118654752440));
    __syncthreads();
    if (tid < 16){
      double s0=0.0, s1=0.0;
      for (int k = 0; k < 128; k += 2){
        s0 += hd[k]   * (double)Wg2[(k)*16 + tid];
        s1 += hd[k+1] * (double)Wg2[(k+1)*16 + tid];
      }
      ld[tid] = (double)bg2[tid] + s0 + s1;
    }
    __syncthreads();
    if (tid == 0){
      int2 olde = gate_e[t];
      double b1 = -1e300, b2 = -1e300; int e1 = 0, e2 = 0;
      for (int e = 0; e < 16; ++e){
        double v = ld[e];
        if (v > b1){ b2 = b1; e2 = e1; b1 = v; e1 = e; }
        else if (v > b2){ b2 = v; e2 = e; }
      }
      double s = 0.0;
      for (int e = 0; e < 16; ++e) s += exp(ld[e] - b1);
      double inv = 1.0 / s;
      int oldp = min(olde.x, olde.y)*16 + max(olde.x, olde.y);
      int newp = min(e1, e2)*16 + max(e1, e2);
      if (oldp != newp){ atomicSub(&counts[oldp], 1); atomicAdd(&counts[newp], 1); }
      gate_e[t] = make_int2(e1, e2);
      gate_g[t] = make_float2((float)(inv + 1e-4), (float)(exp(b2 - b1) * inv + 1e-4));
    }
  }
}

// ---- kscatter: fused scan + scatter.
__global__ __launch_bounds__(256) void kscatter(
    const int2* __restrict__ gate_e, const float2* __restrict__ gate_g,
    const int* __restrict__ counts,
    int* __restrict__ bases, int* __restrict__ cursors,
    int* __restrict__ tile_pair, int* __restrict__ tile_row0, int* __restrict__ ntiles,
    int* __restrict__ pair_tok, float2* __restrict__ pair_g, int ts)
{
  __shared__ int h[256];
  __shared__ int gb[256];
  __shared__ int bl[257];
  int tid = threadIdx.x;
  h[tid] = 0;
  if (tid < 64){
    int l = tid;
    int4 c = *(const int4*)(counts + l*4);
    int s = c.x + c.y + c.z + c.w;
    int ps = s;
    #pragma unroll
    for (int d = 1; d < 64; d <<= 1){ int v = __shfl_up(ps, d); if (l >= d) ps += v; }
    int ex = ps - s;
    bl[4*l+0] = ex;
    bl[4*l+1] = ex + c.x;
    bl[4*l+2] = ex + c.x + c.y;
    bl[4*l+3] = ex + c.x + c.y + c.z;
    if (l == 63) bl[256] = ex + s;
    if (blockIdx.x == 0){
      *(int4*)(bases + 4*l) = make_int4(bl[4*l], bl[4*l+1], bl[4*l+2], bl[4*l+3]);
      if (l == 63) bases[256] = ex + s;
      int t0 = (c.x + ts-1)/ts, t1 = (c.y + ts-1)/ts, t2 = (c.z + ts-1)/ts, t3 = (c.w + ts-1)/ts;
      int tsum = t0 + t1 + t2 + t3;
      int pt = tsum;
      #pragma unroll
      for (int d = 1; d < 64; d <<= 1){ int v = __shfl_up(pt, d); if (l >= d) pt += v; }
      int ext = pt - tsum;
      if (l == 63) *ntiles = ext + tsum;
      int tb = ext;
      int cc[4] = {c.x, c.y, c.z, c.w};
      #pragma unroll
      for (int j = 0; j < 4; ++j){
        int pp = 4*l + j;
        for (int r = 0; r < cc[j]; r += ts){ tile_pair[tb] = pp; tile_row0[tb] = r; ++tb; }
      }
    }
  }
  __syncthreads();
  int t = blockIdx.x*256 + tid;
  int2 ee = gate_e[t]; float2 gg = gate_g[t];
  int a, b; float ga, gbv;
  if (ee.x < ee.y){ a = ee.x; b = ee.y; ga = gg.x; gbv = gg.y; }
  else            { a = ee.y; b = ee.x; ga = gg.y; gbv = gg.x; }
  int p = a*16 + b;
  int off = atomicAdd(&h[p], 1);
  __syncthreads();
  if (h[tid]) gb[tid] = bl[tid] + atomicAdd(&cursors[tid], h[tid]);
  __syncthreads();
  int slot = gb[p] + off;
  pair_tok[slot] = t;
  pair_g[slot] = make_float2(ga, gbv);
}

// ======== kexpert3: 256 tok x 128 cols, BK=32, per-wave 64x64, 3-buf LDS ========
// 512 thr = 8 waves (4M x 2N); acc[4][4] (64 regs) -> 4 waves/SIMD; LDS 75KB ->
// 2 blocks/CU (16 waves/CU). Per K-tile: {8 ds_read + stage(t+2) + vmcnt(3)} ->
// barrier -> lgkm(0) -> 16 MFMA -> barrier.  32 K-tiles (16/expert).
#define SB0 __builtin_amdgcn_sched_barrier(0)

__global__ __launch_bounds__(512, 4) void kexpert3(
    const f16* __restrict__ xbf, const f16* __restrict__ Wt, const float* __restrict__ be,
    float* __restrict__ out,
    const int* __restrict__ counts, const int* __restrict__ bases,
    const int* __restrict__ tile_pair, const int* __restrict__ tile_row0, const int* __restrict__ ntiles,
    const int* __restrict__ pair_tok, const float2* __restrict__ pair_g)
{
  __shared__ __align__(16) char sm[76800];
  const int ABASE = 0, BBASE = 49152, LTOK = 73728, LG = 74752;
  int bid = blockIdx.x;
  int tile = ((bid >> 5) << 3) | (bid & 7);   // 8 tiles x 4 col-blocks per 32-bid group
  int nt = (bid >> 3) & 3;
  if (tile >= *ntiles) return;
  int p = tile_pair[tile], row0 = tile_row0[tile];
  int base = bases[p], cnt = counts[p];
  int eA = p >> 4, eB = p & 15;
  int tid = threadIdx.x, lane = tid & 63, w = tid >> 6;
  int wm = w >> 1, wn = w & 1;
  int l15 = lane & 15, l4 = lane >> 4;
  if (tid < 256){
    int rr = row0 + tid; bool v = rr < cnt;
    ((int*)(sm + LTOK))[tid] = v ? pair_tok[base + rr] : -1;
    ((float2*)(sm + LG))[tid] = v ? pair_g[base + rr] : make_float2(0.f, 1.f);
  }
  __syncthreads();

  int rr = tid >> 2;                                 // 0..127
  int swz = ((tid & 3) ^ (rr & 3)) << 4;
  const char* xb = (const char*)xbf;
  const char* srcA[2];
  #pragma unroll
  for (int i = 0; i < 2; ++i){
    int tk = ((const int*)(sm + LTOK))[i*128 + rr];
    if (tk < 0) tk = 0;
    srcA[i] = xb + (size_t)tk*1024 + swz;
  }
  const char* srcB0 = (const char*)Wt + (size_t)eA*524288 + (size_t)(nt*128 + rr)*1024 + swz;
  long long edelt = ((long long)eB - eA) * 524288;
  int wbase = w*1024;

  auto stA = [&](int t, int bf_){
    if (t >= 32) return;
    int ks = t & 15;
    load_lds16(srcA[0] + ks*64, sm + ABASE + bf_*16384 + wbase);
    load_lds16(srcA[1] + ks*64, sm + ABASE + bf_*16384 + 8192 + wbase);
  };
  auto stB = [&](int t, int bf_){
    if (t >= 32) return;
    int ks = t & 15;
    long long eo = ((t >= 16) ? edelt : 0) + ks*64;
    load_lds16(srcB0 + eo, sm + BBASE + bf_*8192 + wbase);
  };

  f32x4 acc[4][4];
  #pragma unroll
  for (int m = 0; m < 4; ++m)
    #pragma unroll
    for (int n = 0; n < 4; ++n) acc[m][n] = (f32x4){0.f,0.f,0.f,0.f};

  // prologue: stage t0->buf0, t1->buf1 (3 loads each)
  stA(0, 0); stB(0, 0); stA(1, 1); stB(1, 1);
  asm volatile("s_waitcnt vmcnt(3)"); SB0;
  __builtin_amdgcn_s_barrier();

  int bcur = 0, bstg = 2;
  f16x8 af[4], bb[4];
  #pragma unroll 1
  for (int t = 0; t < 32; ++t){
    const char* Ab = sm + ABASE + bcur*16384;
    const char* Bb = sm + BBASE + bcur*8192;
    #pragma unroll
    for (int m = 0; m < 4; ++m) af[m] = readF32h(Ab, wm*64 + m*16 + l15, l4);
    #pragma unroll
    for (int n = 0; n < 4; ++n) bb[n] = readF32h(Bb, wn*64 + n*16 + l15, l4);
    stA(t+2, bstg); stB(t+2, bstg);               // writes buf (t+2)%3 != read bufs
    if (t < 30)       { asm volatile("s_waitcnt vmcnt(3)"); SB0; }
    else if (t == 30) { asm volatile("s_waitcnt vmcnt(0)"); SB0; }
    __builtin_amdgcn_s_barrier();
    asm volatile("s_waitcnt lgkmcnt(0)"); SB0;
    __builtin_amdgcn_s_setprio(1);
    #pragma unroll
    for (int m = 0; m < 4; ++m)
      #pragma unroll
      for (int n = 0; n < 4; ++n)
        acc[m][n] = MFMAH(af[m], bb[n], acc[m][n]);
    __builtin_amdgcn_s_setprio(0);
    SB0;
    __builtin_amdgcn_s_barrier();
    if (t == 15){            // expert switch: fold gate-A into accumulator
      #pragma unroll
      for (int m = 0; m < 4; ++m)
        #pragma unroll
        for (int j = 0; j < 4; ++j){
          int row = wm*64 + m*16 + l4*4 + j;
          float2 g2 = ((const float2*)(sm + LG))[row];
          float r_ = g2.x / g2.y;
          #pragma unroll
          for (int n = 0; n < 4; ++n) acc[m][n][j] *= r_;
        }
    }
    bcur = (bcur == 2) ? 0 : bcur + 1;
    bstg = (bstg == 2) ? 0 : bstg + 1;
  }

  // epilogue: out = gB*acc + gA*bA + gB*bB
  float bcA[4], bcB[4];
  #pragma unroll
  for (int n = 0; n < 4; ++n){
    int col = nt*128 + wn*64 + n*16 + l15;
    bcA[n] = be[(size_t)eA*DDIM + col];
    bcB[n] = be[(size_t)eB*DDIM + col];
  }
  #pragma unroll
  for (int m = 0; m < 4; ++m)
    #pragma unroll
    for (int j = 0; j < 4; ++j){
      int row = wm*64 + m*16 + l4*4 + j;
      int tk = ((const int*)(sm + LTOK))[row];
      if (tk >= 0){
        float2 g2 = ((const float2*)(sm + LG))[row];
        float* orow = out + (size_t)tk*DDIM + nt*128 + wn*64;
        #pragma unroll
        for (int n = 0; n < 4; ++n)
          orow[n*16 + l15] = g2.y*acc[m][n][j] + g2.x*bcA[n] + g2.y*bcB[n];
      }
    }
}

// ---- kexpertF: fallback (no x-f16 room): 128x128 pair-bucket GEMM, reg-staged A.
__global__ __launch_bounds__(256, 2) void kexpertF(
    const float* __restrict__ x,
    const f16* __restrict__ Wt, const float* __restrict__ be,
    float* __restrict__ out,
    const int* __restrict__ counts, const int* __restrict__ bases,
    const int* __restrict__ tile_pair, const int* __restrict__ tile_row0, const int* __restrict__ ntiles,
    const int* __restrict__ pair_tok, const float2* __restrict__ pair_g)
{
  __shared__ __align__(16) char sm[67072];
  const int ABUF = 0, BBUF = 32768, LTOK = 65536, LGOFF = 66048;
  int tile = blockIdx.x >> 2, nt = blockIdx.x & 3;
  if (tile >= *ntiles) return;
  int p = tile_pair[tile], row0 = tile_row0[tile];
  int base = bases[p], cnt = counts[p];
  int eA = p >> 4, eB = p & 15;
  int tid = threadIdx.x, lane = tid & 63;
  int w = tid >> 6, wm = w >> 1, wn = w & 1;
  if (tid < 128){
    int rr = row0 + tid; bool v = rr < cnt;
    ((int*)(sm + LTOK))[tid] = v ? pair_tok[base + rr] : -1;
    ((float2*)(sm + LGOFF))[tid] = v ? pair_g[base + rr] : make_float2(0.f, 0.f);
  }
  __syncthreads();
  const char* wb = (const char*)Wt;
  int grp = tid >> 3, gch = tid & 7;
  int swz = (gch ^ (grp & 7)) << 4;
  long long edelt = ((long long)eB - (long long)eA) * 524288;
  const char* srcB[4];
  #pragma unroll
  for (int i = 0; i < 4; ++i)
    srcB[i] = wb + (long long)eA*524288 + (size_t)(nt*128 + i*32 + grp)*1024 + swz;
  int arow = tid >> 1, ach = tid & 1;
  int tkr = ((const int*)(sm + LTOK))[arow];
  if (tkr < 0) tkr = 0;
  const float* xrow = x + (size_t)tkr*DDIM + ach*32;
  int ldst = (w << 10);
  #pragma unroll
  for (int i = 0; i < 4; ++i) load_lds16(srcB[i], sm + BBUF + i*4096 + ldst);
  {
    #pragma unroll
    for (int q2 = 0; q2 < 4; ++q2){
      float fv[8];
      *(float4*)&fv[0] = *(const float4*)(xrow + q2*8);
      *(float4*)&fv[4] = *(const float4*)(xrow + q2*8 + 4);
      f16x8 hv = pack8f(fv);
      int g = ach*4 + q2;
      *(f16x8*)(sm + ABUF + arow*128 + ((g ^ (arow & 7)) << 4)) = hv;
    }
  }
  f32x4 acc[4][4], res[4][4];
  #pragma unroll
  for (int m=0;m<4;++m)
    #pragma unroll
    for (int n=0;n<4;++n) acc[m][n] = (f32x4){0.f,0.f,0.f,0.f};
  for (int u = 0; u < 16; ++u){
    int b = u & 1;
    asm volatile("s_waitcnt vmcnt(0)" ::: "memory");
    __syncthreads();
    int un = u + 1;
    f16x8 hv[4];
    if (un < 16){
      int b2 = un & 1;
      long long aoff = (long long)(un & 7) * 128;
      long long boff = aoff + ((un >> 3) ? edelt : 0);
      #pragma unroll
      for (int i = 0; i < 4; ++i)
        load_lds16(srcB[i] + boff, sm + BBUF + b2*16384 + i*4096 + ldst);
      const float* xr = xrow + (un & 7)*64;
      #pragma unroll
      for (int q2 = 0; q2 < 4; ++q2){
        float fv[8];
        *(float4*)&fv[0] = *(const float4*)(xr + q2*8);
        *(float4*)&fv[4] = *(const float4*)(xr + q2*8 + 4);
        hv[q2] = pack8f(fv);
      }
    }
    const char* Ab = sm + ABUF + b*16384;
    const char* Bb = sm + BBUF + b*16384;
    f16x8 af2[4][2], bf2[4][2];
    #pragma unroll
    for (int m=0;m<4;++m){
      int r = wm*64 + m*16 + (lane & 15);
      af2[m][0] = readF64h(Ab, r, (lane >> 4));
      af2[m][1] = readF64h(Ab, r, 4 + (lane >> 4));
    }
    #pragma unroll
    for (int n=0;n<4;++n){
      int r = wn*64 + n*16 + (lane & 15);
      bf2[n][0] = readF64h(Bb, r, (lane >> 4));
      bf2[n][1] = readF64h(Bb, r, 4 + (lane >> 4));
    }
    #pragma unroll
    for (int m=0;m<4;++m)
      #pragma unroll
      for (int n=0;n<4;++n){
        acc[m][n] = MFMAH(af2[m][0], bf2[n][0], acc[m][n]);
        acc[m][n] = MFMAH(af2[m][1], bf2[n][1], acc[m][n]);
      }
    if (un < 16){
      int b2 = un & 1;
      #pragma unroll
      for (int q2 = 0; q2 < 4; ++q2){
        int g = ach*4 + q2;
        *(f16x8*)(sm + ABUF + b2*16384 + arow*128 + ((g ^ (arow & 7)) << 4)) = hv[q2];
      }
    }
    if (u == 7){
      const float* bev = be + (size_t)eA*DDIM + nt*128;
      float bcol[4];
      #pragma unroll
      for (int n=0;n<4;++n) bcol[n] = bev[wn*64 + n*16 + (lane & 15)];
      #pragma unroll
      for (int m=0;m<4;++m)
        #pragma unroll
        for (int j=0;j<4;++j){
          int row = wm*64 + m*16 + ((lane >> 4) << 2) + j;
          float g = ((const float2*)(sm + LGOFF))[row].x;
          #pragma unroll
          for (int n=0;n<4;++n){
            res[m][n][j] = g * (acc[m][n][j] + bcol[n]);
            acc[m][n][j] = 0.f;
          }
        }
    }
    if (u == 15){
      const float* bev = be + (size_t)eB*DDIM + nt*128;
      float bcol[4];
      #pragma unroll
      for (int n=0;n<4;++n) bcol[n] = bev[wn*64 + n*16 + (lane & 15)];
      #pragma unroll
      for (int m=0;m<4;++m)
        #pragma unroll
        for (int j=0;j<4;++j){
          int row = wm*64 + m*16 + ((lane >> 4) << 2) + j;
          int tk = ((const int*)(sm + LTOK))[row];
          float g = ((const float2*)(sm + LGOFF))[row].y;
          if (tk >= 0){
            float* orow = out + (size_t)tk*DDIM + nt*128;
            #pragma unroll
            for (int n=0;n<4;++n)
              orow[wn*64 + n*16 + (lane & 15)] = res[m][n][j] + g * (acc[m][n][j] + bcol[n]);
          }
        }
    }
  }
}

// ---- host launch --------------------------------------------------------------
extern "C" void kernel_launch(void* const* d_in, const int* in_sizes, int n_in,
                              void* d_out, int out_size, void* d_ws, size_t ws_size,
                              hipStream_t stream)
{
  const float* x   = (const float*)d_in[0];
  const float* Wg1 = (const float*)d_in[1];
  const float* bg1 = (const float*)d_in[2];
  const float* Wg2 = (const float*)d_in[3];
  const float* bg2 = (const float*)d_in[4];
  const float* We  = (const float*)d_in[5];
  const float* be  = (const float*)d_in[6];
  float* out = (float*)d_out;
  char* ws = (char*)d_ws;

  f16*  Wt          = (f16*)(ws + 0);             // 8,388,608
  f16*  W1          = (f16*)(ws + 8388608);       //   131,072
  char* Wg2f        = ws + 8519680;               //     4,096
  char* CTRL        = ws + 8650752;               //     8,192
  int*  refine_cnt  = (int*)(CTRL);
  int*  ntiles      = (int*)(CTRL + 4);
  int*  counts      = (int*)(CTRL + 64);          // 256 ints
  int*  cursors     = (int*)(CTRL + 2048);        // 256 ints
  int*  bases       = (int*)(CTRL + 4096);        // 257 ints
  int2*   gate_e    = (int2*)(ws + 8658944);      // 1,048,576
  float2* gate_g    = (float2*)(ws + 9707520);    // 1,048,576
  int*  refine_list = (int*)(ws + 10756096);      //   524,288
  int*  pair_tok    = (int*)(ws + 11280384);      //   524,288
  float2* pair_g    = (float2*)(ws + 11804672);   // 1,048,576
  int*  tile_pair   = (int*)(ws + 12853248);      //    10,240
  int*  tile_row0   = (int*)(ws + 12863488);      //    10,240
  const size_t XBF_OFF = 16777216ull;
  const size_t XBF_BYTES = (size_t)NTOK * DDIM * 2;   // 134 MB (f16 x)
  bool bf16a = ws_size >= XBF_OFF + XBF_BYTES;
  f16* xbf = bf16a ? (f16*)(ws + XBF_OFF) : nullptr;

  hipLaunchKernelGGL(kconv,    dim3(17),   dim3(256), 0, stream, Wg1, Wg2, W1, Wg2f,
                     (int*)CTRL);
  hipLaunchKernelGGL(kgate,    dim3(1024), dim3(256), 0, stream, x, W1, Wg2f, bg1, bg2,
                     We, Wt, xbf, gate_e, gate_g, refine_cnt, refine_list, counts);
  hipLaunchKernelGGL(krefine,  dim3(512),  dim3(128), 0, stream, x, Wg1, bg1, Wg2, bg2,
                     refine_cnt, refine_list, gate_e, gate_g, counts);
  hipLaunchKernelGGL(kscatter, dim3(512),  dim3(256), 0, stream, gate_e, gate_g, counts,
                     bases, cursors, tile_pair, tile_row0, ntiles, pair_tok, pair_g,
                     bf16a ? 256 : 128);
  if (bf16a)
    hipLaunchKernelGGL(kexpert3, dim3(2816), dim3(512), 0, stream, xbf, Wt, be, out,
                       counts, bases, tile_pair, tile_row0, ntiles, pair_tok, pair_g);
  else
    hipLaunchKernelGGL(kexpertF, dim3(5120), dim3(256), 0, stream, x, Wt, be, out,
                       counts, bases, tile_pair, tile_row0, ntiles, pair_tok, pair_g);
  (void)in_sizes; (void)n_in; (void)out_size; (void)ws_size;
}

// Round 10
// 410.026 us; speedup vs baseline: 1.1429x; 1.1429x over previous
//
#include <hip/hip_runtime.h>
#include <cstdint>
#include <math.h>

// MoE top-2 of 16 experts. N=131072, D=512, H=128, E=16, O=512.  All-fp16 path:
//   kconv (Wg1->W1 f16 [H][D], Wg2->frag-order f16, CTRL zero; 17 blocks)
//   -> kgate (128 tok/block fp16 MFMA gating + x-f16 store + pair histogram;
//             tail converts one We tile -> Wt f16 [O][D] per block)
//   -> krefine (fp64 exact gating for flagged tokens; patches counts)
//   -> kscatter (fused block-local scan + scatter; block 0 writes bases/tile list)
//   -> kexpert4 (pair-bucket f16 GEMM, 256 tok x 128 cols, BK=32, per-wave 64x64
//      (acc=64 regs -> 4 waves/SIMD), triple-buffered LDS, 2-rows-per-128B-line
//      packed tiles (bank-conflict-free at BK=32), counted vmcnt(3);
//      gate-A folded into accumulator; single store)

#define NTOK 131072
#define DDIM 512

typedef _Float16 f16;
typedef f16   f16x8 __attribute__((ext_vector_type(8)));
typedef float f32x4 __attribute__((ext_vector_type(4)));

__device__ __forceinline__ void load_lds16(const void* g, void* l){
  __builtin_amdgcn_global_load_lds(
      (const __attribute__((address_space(1))) void*)(uintptr_t)g,
      (__attribute__((address_space(3))) void*)(uintptr_t)l, 16, 0, 0);
}

__device__ __forceinline__ f32x4 MFMAH(f16x8 a, f16x8 b, f32x4 c){
  return __builtin_amdgcn_mfma_f32_16x16x32_f16(a, b, c, 0, 0, 0);
}

// ---- swizzled LDS helpers -----------------------------------------------------
// 64-col f16 tile (pitch 128B): logical (row r, 16B chunk q) at r*128+((q^(r&7))<<4)
__device__ __forceinline__ f16x8 readF64h(const char* buf, int r, int q){
  return *(const f16x8*)(buf + r*128 + ((q ^ (r & 7)) << 4));
}
// 32-k f16 tile PACKED 2 rows/128B line: (r, q) at line=r>>1,
// slot=(((r&1)<<2)|q) ^ (line&7).  Conflict-free for 16-row fragment reads.
__device__ __forceinline__ f16x8 readP32(const char* buf, int r, int q){
  int line = r >> 1;
  int slot = (((r & 1) << 2) | q) ^ (line & 7);
  return *(const f16x8*)(buf + line*128 + (slot << 4));
}
__device__ __forceinline__ f16x8 pack8f(const float* fv){
  f16x8 v;
  #pragma unroll
  for (int j=0;j<8;++j) v[j] = (f16)fv[j];   // RNE v_cvt_f16_f32
  return v;
}

// ---- kconv: Wg1 [D][H] f32 -> W1 f16 [H][D]; Wg2 -> frag-order f16; CTRL zero.
__global__ void kconv(const float* __restrict__ Wg1, const float* __restrict__ Wg2,
                      f16* __restrict__ W1, char* __restrict__ Wg2f, int* __restrict__ ctrl){
  __shared__ float sh[64*65];
  int bx = blockIdx.x, tid = threadIdx.x;
  if (bx < 16){
    int dt = bx >> 1, ht = bx & 1;
    const float* src = Wg1 + (size_t)dt*64*128 + ht*64;
    #pragma unroll
    for (int it=0; it<16; ++it){ int idx = it*256+tid; int dl = idx>>6, ol = idx&63;
      sh[dl*65+ol] = src[dl*128+ol]; }
    __syncthreads();
    #pragma unroll
    for (int it=0; it<16; ++it){ int idx = it*256+tid; int ol = idx>>6, dl = idx&63;
      W1[(size_t)(ht*64+ol)*512 + dt*64+dl] = (f16)sh[dl*65+ol]; }
  } else {
    int ks = tid >> 6, l = tid & 63;
    int col = l & 15, kb = ks*32 + ((l >> 4) << 3);
    f16x8 v;
    #pragma unroll
    for (int j=0;j<8;++j) v[j] = (f16)Wg2[(kb+j)*16 + col];
    *(f16x8*)(Wg2f + (ks*64+l)*16) = v;
    #pragma unroll
    for (int i = 0; i < 8; ++i) ctrl[tid + i*256] = 0;   // zero CTRL (8KB)
  }
}

// ---- kgate: 128 tok/block fp16 gating + x-f16 producer + pair histogram.
__global__ __launch_bounds__(256) void kgate(
    const float* __restrict__ x, const f16* __restrict__ W1, const char* __restrict__ Wg2f,
    const float* __restrict__ bg1, const float* __restrict__ bg2,
    const float* __restrict__ We, f16* __restrict__ Wt,
    f16* __restrict__ xbf,
    int2* __restrict__ gate_e, float2* __restrict__ gate_g,
    int* __restrict__ refine_cnt, int* __restrict__ refine_list, int* __restrict__ counts)
{
  __shared__ __align__(16) char sm[76800];
  const int BOFF = 32768;
  const int LOGI = 67584;
  const int HIST = 75776;
  int tid = threadIdx.x, bid = blockIdx.x;
  int lane = tid & 63, w = tid >> 6, wm = w >> 1, wn = w & 1;
  int l15 = lane & 15, l4 = lane >> 4;
  int t0 = bid * 128;
  int ar = tid >> 1, ach = tid & 1;
  const float* xrow = x + (size_t)(t0 + ar) * DDIM;
  char* xbfb = (char*)xbf;
  f32x4 acc[4][4];
  #pragma unroll
  for (int n=0;n<4;++n){
    float bb = bg1[wn*64 + n*16 + l15];
    f32x4 z = {bb, bb, bb, bb};
    #pragma unroll
    for (int m=0;m<4;++m) acc[m][n] = z;
  }
  auto stageA = [&](int ks, char* abuf){
    float fv[32];
    #pragma unroll
    for (int q=0;q<8;++q) *(float4*)&fv[q*4] = *(const float4*)(xrow + ks*64 + ach*32 + q*4);
    f16x8 h0 = pack8f(fv), h1 = pack8f(fv+8), h2 = pack8f(fv+16), h3 = pack8f(fv+24);
    *(f16x8*)(abuf + ar*128 + (((ach*4+0) ^ (ar & 7)) << 4)) = h0;
    *(f16x8*)(abuf + ar*128 + (((ach*4+1) ^ (ar & 7)) << 4)) = h1;
    *(f16x8*)(abuf + ar*128 + (((ach*4+2) ^ (ar & 7)) << 4)) = h2;
    *(f16x8*)(abuf + ar*128 + (((ach*4+3) ^ (ar & 7)) << 4)) = h3;
    if (xbf){
      char* xd = xbfb + (size_t)(t0+ar)*1024 + ks*128 + ach*64;
      *(f16x8*)xd = h0; *(f16x8*)(xd+16) = h1; *(f16x8*)(xd+32) = h2; *(f16x8*)(xd+48) = h3;
    }
  };
  auto stageB = [&](int ks, char* lds){
    const char* gb = (const char*)W1 + ks*128;
    #pragma unroll
    for (int i = 0; i < 4; ++i){
      int lin = i*4096 + tid*16;
      int r = lin >> 7, g = (lin >> 4) & 7;
      load_lds16(gb + r*1024 + ((g ^ (r & 7)) << 4), lds + i*4096 + ((tid >> 6) << 10));
    }
  };
  stageB(0, sm + BOFF); stageA(0, sm);
  for (int ks = 0; ks < 8; ++ks){
    int b = ks & 1;
    asm volatile("s_waitcnt vmcnt(0)" ::: "memory");
    __syncthreads();
    if (ks < 7) stageB(ks+1, sm + BOFF + (b^1)*16384);
    const char* Ab = sm + b*16384;
    const char* Bb = sm + BOFF + b*16384;
    f16x8 ah[4][2], bh[4][2];
    #pragma unroll
    for (int m=0;m<4;++m)
      #pragma unroll
      for (int kf=0;kf<2;++kf) ah[m][kf] = readF64h(Ab, wm*64 + m*16 + l15, kf*4 + l4);
    #pragma unroll
    for (int n=0;n<4;++n)
      #pragma unroll
      for (int kf=0;kf<2;++kf) bh[n][kf] = readF64h(Bb, wn*64 + n*16 + l15, kf*4 + l4);
    #pragma unroll
    for (int m=0;m<4;++m)
      #pragma unroll
      for (int n=0;n<4;++n){
        acc[m][n] = MFMAH(ah[m][0], bh[n][0], acc[m][n]);
        acc[m][n] = MFMAH(ah[m][1], bh[n][1], acc[m][n]);
      }
    if (ks < 7) stageA(ks+1, sm + (b^1)*16384);
  }
  __syncthreads();
  uint4 wgf[4];
  #pragma unroll
  for (int ksq=0; ksq<4; ++ksq) wgf[ksq] = *(const uint4*)(Wg2f + (ksq*64+lane)*16);
  float* hl = (float*)sm;
  #pragma unroll
  for (int m=0;m<4;++m)
    #pragma unroll
    for (int n=0;n<4;++n)
      #pragma unroll
      for (int j=0;j<4;++j){
        int row = wm*64 + m*16 + (l4 << 2) + j;
        int col = wn*64 + n*16 + l15;
        float uv = acc[m][n][j];
        hl[row*132 + col] = 0.5f * uv * (1.0f + erff(uv * 0.70710678118654752f));
      }
  __syncthreads();
  {
    float bb2 = bg2[l15];
    float* ll = (float*)(sm + LOGI);
    #pragma unroll
    for (int sub=0; sub<2; ++sub){
      f32x4 acc2 = {bb2, bb2, bb2, bb2};
      #pragma unroll
      for (int ksq=0; ksq<4; ++ksq){
        const float* hp = (const float*)sm + (w*32 + sub*16 + l15)*132 + ksq*32 + l4*8;
        f16x8 afr;
        #pragma unroll
        for (int j=0;j<8;++j) afr[j] = (f16)hp[j];
        acc2 = MFMAH(afr, *(const f16x8*)&wgf[ksq], acc2);
      }
      #pragma unroll
      for (int j=0;j<4;++j) ll[(w*32 + sub*16 + l4*4 + j)*16 + l15] = acc2[j];
    }
  }
  int* hist = (int*)(sm + HIST);
  hist[tid] = 0;
  __syncthreads();
  if (tid < 128){
    int t = t0 + tid;
    const float* l = (const float*)(sm + LOGI) + tid*16;
    float b1 = -1e30f, b2 = -1e30f, b3 = -1e30f; int e1 = 0, e2 = 0;
    #pragma unroll
    for (int e = 0; e < 16; ++e){
      float v = l[e];
      if (v > b1){ b3 = b2; b2 = b1; e2 = e1; b1 = v; e1 = e; }
      else if (v > b2){ b3 = b2; b2 = v; e2 = e; }
      else if (v > b3){ b3 = v; }
    }
    float s = 0.f;
    #pragma unroll
    for (int e = 0; e < 16; ++e) s += expf(l[e] - b1);
    float inv = 1.f / s;
    gate_e[t] = make_int2(e1, e2);
    gate_g[t] = make_float2(inv + 1e-4f, expf(b2 - b1) * inv + 1e-4f);
    if (b2 - b3 < 4e-4f){            // fp16-path margin (~6.7 sigma of logit err)
      int pos = atomicAdd(refine_cnt, 1);
      refine_list[pos] = t;
    }
    int pa = min(e1, e2), pb = max(e1, e2);
    atomicAdd(&hist[pa*16 + pb], 1);
  }
  __syncthreads();
  if (hist[tid]) atomicAdd(&counts[tid], hist[tid]);
  // ---- tail: convert one We 64x64 tile -> Wt (fused kconv work) ----
  __syncthreads();
  {
    float* sh = (float*)sm;
    int e = bid >> 6, dt = (bid >> 3) & 7, ot = bid & 7;
    const float* src = We + (size_t)e*262144 + (size_t)dt*64*512 + ot*64;
    #pragma unroll
    for (int it=0; it<16; ++it){ int idx = it*256+tid; int dl = idx>>6, ol = idx&63;
      sh[dl*65+ol] = src[dl*512+ol]; }
    __syncthreads();
    f16* dst = Wt + (size_t)e*262144 + (size_t)ot*64*512 + dt*64;
    #pragma unroll
    for (int it=0; it<16; ++it){ int idx = it*256+tid; int ol = idx>>6, dl = idx&63;
      dst[(size_t)ol*512+dl] = (f16)sh[dl*65+ol]; }
  }
}

// ---- krefine: exact fp64 gating for flagged tokens (4-way chains); patches counts.
__global__ __launch_bounds__(128) void krefine(
    const float* __restrict__ x, const float* __restrict__ Wg1, const float* __restrict__ bg1,
    const float* __restrict__ Wg2, const float* __restrict__ bg2,
    const int* __restrict__ refine_cnt, const int* __restrict__ refine_list,
    int2* __restrict__ gate_e, float2* __restrict__ gate_g, int* __restrict__ counts)
{
  __shared__ float  xs[512];
  __shared__ double hd[128];
  __shared__ double ld[16];
  int tid = threadIdx.x;
  int rc = *refine_cnt;
  for (int i = blockIdx.x; i < rc; i += gridDim.x){
    __syncthreads();
    int t = refine_list[i];
    *(float4*)(xs + tid*4) = *(const float4*)(x + (size_t)t*DDIM + tid*4);
    __syncthreads();
    double a0=0.0, a1=0.0, a2=0.0, a3=0.0;
    for (int d = 0; d < 512; d += 4){
      a0 += (double)xs[d]   * (double)Wg1[(d)*128 + tid];
      a1 += (double)xs[d+1] * (double)Wg1[(d+1)*128 + tid];
      a2 += (double)xs[d+2] * (double)Wg1[(d+2)*128 + tid];
      a3 += (double)xs[d+3] * (double)Wg1[(d+3)*128 + tid];
    }
    double a = (double)bg1[tid] + ((a0+a1)+(a2+a3));
    hd[tid] = 0.5 * a * (1.0 + erf(a * 0.70710678118654752440));
    __syncthreads();
    if (tid < 16){
      double s0=0.0, s1=0.0;
      for (int k = 0; k < 128; k += 2){
        s0 += hd[k]   * (double)Wg2[(k)*16 + tid];
        s1 += hd[k+1] * (double)Wg2[(k+1)*16 + tid];
      }
      ld[tid] = (double)bg2[tid] + s0 + s1;
    }
    __syncthreads();
    if (tid == 0){
      int2 olde = gate_e[t];
      double b1 = -1e300, b2 = -1e300; int e1 = 0, e2 = 0;
      for (int e = 0; e < 16; ++e){
        double v = ld[e];
        if (v > b1){ b2 = b1; e2 = e1; b1 = v; e1 = e; }
        else if (v > b2){ b2 = v; e2 = e; }
      }
      double s = 0.0;
      for (int e = 0; e < 16; ++e) s += exp(ld[e] - b1);
      double inv = 1.0 / s;
      int oldp = min(olde.x, olde.y)*16 + max(olde.x, olde.y);
      int newp = min(e1, e2)*16 + max(e1, e2);
      if (oldp != newp){ atomicSub(&counts[oldp], 1); atomicAdd(&counts[newp], 1); }
      gate_e[t] = make_int2(e1, e2);
      gate_g[t] = make_float2((float)(inv + 1e-4), (float)(exp(b2 - b1) * inv + 1e-4));
    }
  }
}

// ---- kscatter: fused scan + scatter.
__global__ __launch_bounds__(256) void kscatter(
    const int2* __restrict__ gate_e, const float2* __restrict__ gate_g,
    const int* __restrict__ counts,
    int* __restrict__ bases, int* __restrict__ cursors,
    int* __restrict__ tile_pair, int* __restrict__ tile_row0, int* __restrict__ ntiles,
    int* __restrict__ pair_tok, float2* __restrict__ pair_g, int ts)
{
  __shared__ int h[256];
  __shared__ int gb[256];
  __shared__ int bl[257];
  int tid = threadIdx.x;
  h[tid] = 0;
  if (tid < 64){
    int l = tid;
    int4 c = *(const int4*)(counts + l*4);
    int s = c.x + c.y + c.z + c.w;
    int ps = s;
    #pragma unroll
    for (int d = 1; d < 64; d <<= 1){ int v = __shfl_up(ps, d); if (l >= d) ps += v; }
    int ex = ps - s;
    bl[4*l+0] = ex;
    bl[4*l+1] = ex + c.x;
    bl[4*l+2] = ex + c.x + c.y;
    bl[4*l+3] = ex + c.x + c.y + c.z;
    if (l == 63) bl[256] = ex + s;
    if (blockIdx.x == 0){
      *(int4*)(bases + 4*l) = make_int4(bl[4*l], bl[4*l+1], bl[4*l+2], bl[4*l+3]);
      if (l == 63) bases[256] = ex + s;
      int t0 = (c.x + ts-1)/ts, t1 = (c.y + ts-1)/ts, t2 = (c.z + ts-1)/ts, t3 = (c.w + ts-1)/ts;
      int tsum = t0 + t1 + t2 + t3;
      int pt = tsum;
      #pragma unroll
      for (int d = 1; d < 64; d <<= 1){ int v = __shfl_up(pt, d); if (l >= d) pt += v; }
      int ext = pt - tsum;
      if (l == 63) *ntiles = ext + tsum;
      int tb = ext;
      int cc[4] = {c.x, c.y, c.z, c.w};
      #pragma unroll
      for (int j = 0; j < 4; ++j){
        int pp = 4*l + j;
        for (int r = 0; r < cc[j]; r += ts){ tile_pair[tb] = pp; tile_row0[tb] = r; ++tb; }
      }
    }
  }
  __syncthreads();
  int t = blockIdx.x*256 + tid;
  int2 ee = gate_e[t]; float2 gg = gate_g[t];
  int a, b; float ga, gbv;
  if (ee.x < ee.y){ a = ee.x; b = ee.y; ga = gg.x; gbv = gg.y; }
  else            { a = ee.y; b = ee.x; ga = gg.y; gbv = gg.x; }
  int p = a*16 + b;
  int off = atomicAdd(&h[p], 1);
  __syncthreads();
  if (h[tid]) gb[tid] = bl[tid] + atomicAdd(&cursors[tid], h[tid]);
  __syncthreads();
  int slot = gb[p] + off;
  pair_tok[slot] = t;
  pair_g[slot] = make_float2(ga, gbv);
}

// ======== kexpert4: 256 tok x 128 cols, BK=32, per-wave 64x64, 3-buf LDS ========
// 512 thr = 8 waves (4M x 2N); acc 64 regs -> 4 waves/SIMD; LDS 75KB -> 2 blk/CU.
// Tiles PACKED 2 rows per 128B line -> conflict-free fragment reads at BK=32.
// Per K-tile: {8 ds_read + stage(t+2) + vmcnt(3)} -> barrier -> lgkm(0) ->
// 16 MFMA -> barrier.  32 K-tiles (16/expert).
#define SB0 __builtin_amdgcn_sched_barrier(0)

__global__ __launch_bounds__(512, 4) void kexpert4(
    const f16* __restrict__ xbf, const f16* __restrict__ Wt, const float* __restrict__ be,
    float* __restrict__ out,
    const int* __restrict__ counts, const int* __restrict__ bases,
    const int* __restrict__ tile_pair, const int* __restrict__ tile_row0, const int* __restrict__ ntiles,
    const int* __restrict__ pair_tok, const float2* __restrict__ pair_g)
{
  __shared__ __align__(16) char sm[76800];
  const int LTOK = 73728, LG = 74752;    // 3 bufs x 24KB at [0,73728)
  int bid = blockIdx.x;
  int tile = ((bid >> 5) << 3) | (bid & 7);
  int nt = (bid >> 3) & 3;
  if (tile >= *ntiles) return;
  int p = tile_pair[tile], row0 = tile_row0[tile];
  int base = bases[p], cnt = counts[p];
  int eA = p >> 4, eB = p & 15;
  int tid = threadIdx.x, lane = tid & 63, w = tid >> 6;
  int wm = w >> 1, wn = w & 1;
  int l15 = lane & 15, l4 = lane >> 4;
  if (tid < 256){
    int rr = row0 + tid; bool v = rr < cnt;
    ((int*)(sm + LTOK))[tid] = v ? pair_tok[base + rr] : -1;
    ((float2*)(sm + LG))[tid] = v ? pair_g[base + rr] : make_float2(0.f, 1.f);
  }
  __syncthreads();

  // ---- staging source precompute (inverse of the packed layout) ----
  // A: 16KB/tile = 16 slices of 1KB; wave w stages slices w*2, w*2+1.
  const char* xb = (const char*)xbf;
  const char* srcA[2];
  #pragma unroll
  for (int c = 0; c < 2; ++c){
    int slice = w*2 + c;
    int line = slice*8 + (lane >> 3);          // 0..127
    int slotp = (lane & 7) ^ (line & 7);
    int r = (line << 1) | (slotp >> 2);        // token row 0..255
    int q = slotp & 3;                         // 16B k-chunk
    int tk = ((const int*)(sm + LTOK))[r];
    if (tk < 0) tk = 0;
    srcA[c] = xb + (size_t)tk*1024 + q*16;
  }
  // B: 8KB/tile = 8 slices; wave w stages slice w.
  const char* srcB0;
  {
    int line = w*8 + (lane >> 3);              // 0..63
    int slotp = (lane & 7) ^ (line & 7);
    int r = (line << 1) | (slotp >> 2);        // out-col 0..127
    int q = slotp & 3;
    srcB0 = (const char*)Wt + (size_t)eA*524288 + (size_t)(nt*128 + r)*1024 + q*16;
  }
  long long edelt = ((long long)eB - eA) * 524288;

  auto stA = [&](int t, int bf_){
    if (t >= 32) return;
    int ks = t & 15;
    load_lds16(srcA[0] + ks*64, sm + bf_*24576 + (w*2)*1024);
    load_lds16(srcA[1] + ks*64, sm + bf_*24576 + (w*2+1)*1024);
  };
  auto stB = [&](int t, int bf_){
    if (t >= 32) return;
    int ks = t & 15;
    long long eo = ((t >= 16) ? edelt : 0) + ks*64;
    load_lds16(srcB0 + eo, sm + bf_*24576 + 16384 + w*1024);
  };

  f32x4 acc[4][4];
  #pragma unroll
  for (int m = 0; m < 4; ++m)
    #pragma unroll
    for (int n = 0; n < 4; ++n) acc[m][n] = (f32x4){0.f,0.f,0.f,0.f};

  // prologue: stage t0->buf0, t1->buf1 (3 loads each)
  stA(0, 0); stB(0, 0); stA(1, 1); stB(1, 1);
  asm volatile("s_waitcnt vmcnt(3)"); SB0;
  __builtin_amdgcn_s_barrier();

  int bcur = 0, bstg = 2;
  f16x8 af[4], bb[4];
  #pragma unroll 1
  for (int t = 0; t < 32; ++t){
    const char* Ab = sm + bcur*24576;
    const char* Bb = Ab + 16384;
    #pragma unroll
    for (int m = 0; m < 4; ++m) af[m] = readP32(Ab, wm*64 + m*16 + l15, l4);
    #pragma unroll
    for (int n = 0; n < 4; ++n) bb[n] = readP32(Bb, wn*64 + n*16 + l15, l4);
    stA(t+2, bstg); stB(t+2, bstg);
    if (t < 30)       { asm volatile("s_waitcnt vmcnt(3)"); SB0; }
    else if (t == 30) { asm volatile("s_waitcnt vmcnt(0)"); SB0; }
    __builtin_amdgcn_s_barrier();
    asm volatile("s_waitcnt lgkmcnt(0)"); SB0;
    __builtin_amdgcn_s_setprio(1);
    #pragma unroll
    for (int m = 0; m < 4; ++m)
      #pragma unroll
      for (int n = 0; n < 4; ++n)
        acc[m][n] = MFMAH(af[m], bb[n], acc[m][n]);
    __builtin_amdgcn_s_setprio(0);
    SB0;
    __builtin_amdgcn_s_barrier();
    if (t == 15){            // expert switch: fold gate-A into accumulator
      #pragma unroll
      for (int m = 0; m < 4; ++m)
        #pragma unroll
        for (int j = 0; j < 4; ++j){
          int row = wm*64 + m*16 + l4*4 + j;
          float2 g2 = ((const float2*)(sm + LG))[row];
          float r_ = g2.x / g2.y;
          #pragma unroll
          for (int n = 0; n < 4; ++n) acc[m][n][j] *= r_;
        }
    }
    bcur = (bcur == 2) ? 0 : bcur + 1;
    bstg = (bstg == 2) ? 0 : bstg + 1;
  }

  // epilogue: out = gB*acc + gA*bA + gB*bB
  float bcA[4], bcB[4];
  #pragma unroll
  for (int n = 0; n < 4; ++n){
    int col = nt*128 + wn*64 + n*16 + l15;
    bcA[n] = be[(size_t)eA*DDIM + col];
    bcB[n] = be[(size_t)eB*DDIM + col];
  }
  #pragma unroll
  for (int m = 0; m < 4; ++m)
    #pragma unroll
    for (int j = 0; j < 4; ++j){
      int row = wm*64 + m*16 + l4*4 + j;
      int tk = ((const int*)(sm + LTOK))[row];
      if (tk >= 0){
        float2 g2 = ((const float2*)(sm + LG))[row];
        float* orow = out + (size_t)tk*DDIM + nt*128 + wn*64;
        #pragma unroll
        for (int n = 0; n < 4; ++n)
          orow[n*16 + l15] = g2.y*acc[m][n][j] + g2.x*bcA[n] + g2.y*bcB[n];
      }
    }
}

// ---- kexpertF: fallback (no x-f16 room): 128x128 pair-bucket GEMM, reg-staged A.
__global__ __launch_bounds__(256, 2) void kexpertF(
    const float* __restrict__ x,
    const f16* __restrict__ Wt, const float* __restrict__ be,
    float* __restrict__ out,
    const int* __restrict__ counts, const int* __restrict__ bases,
    const int* __restrict__ tile_pair, const int* __restrict__ tile_row0, const int* __restrict__ ntiles,
    const int* __restrict__ pair_tok, const float2* __restrict__ pair_g)
{
  __shared__ __align__(16) char sm[67072];
  const int ABUF = 0, BBUF = 32768, LTOK = 65536, LGOFF = 66048;
  int tile = blockIdx.x >> 2, nt = blockIdx.x & 3;
  if (tile >= *ntiles) return;
  int p = tile_pair[tile], row0 = tile_row0[tile];
  int base = bases[p], cnt = counts[p];
  int eA = p >> 4, eB = p & 15;
  int tid = threadIdx.x, lane = tid & 63;
  int w = tid >> 6, wm = w >> 1, wn = w & 1;
  if (tid < 128){
    int rr = row0 + tid; bool v = rr < cnt;
    ((int*)(sm + LTOK))[tid] = v ? pair_tok[base + rr] : -1;
    ((float2*)(sm + LGOFF))[tid] = v ? pair_g[base + rr] : make_float2(0.f, 0.f);
  }
  __syncthreads();
  const char* wb = (const char*)Wt;
  int grp = tid >> 3, gch = tid & 7;
  int swz = (gch ^ (grp & 7)) << 4;
  long long edelt = ((long long)eB - (long long)eA) * 524288;
  const char* srcB[4];
  #pragma unroll
  for (int i = 0; i < 4; ++i)
    srcB[i] = wb + (long long)eA*524288 + (size_t)(nt*128 + i*32 + grp)*1024 + swz;
  int arow = tid >> 1, ach = tid & 1;
  int tkr = ((const int*)(sm + LTOK))[arow];
  if (tkr < 0) tkr = 0;
  const float* xrow = x + (size_t)tkr*DDIM + ach*32;
  int ldst = (w << 10);
  #pragma unroll
  for (int i = 0; i < 4; ++i) load_lds16(srcB[i], sm + BBUF + i*4096 + ldst);
  {
    #pragma unroll
    for (int q2 = 0; q2 < 4; ++q2){
      float fv[8];
      *(float4*)&fv[0] = *(const float4*)(xrow + q2*8);
      *(float4*)&fv[4] = *(const float4*)(xrow + q2*8 + 4);
      f16x8 hv = pack8f(fv);
      int g = ach*4 + q2;
      *(f16x8*)(sm + ABUF + arow*128 + ((g ^ (arow & 7)) << 4)) = hv;
    }
  }
  f32x4 acc[4][4], res[4][4];
  #pragma unroll
  for (int m=0;m<4;++m)
    #pragma unroll
    for (int n=0;n<4;++n) acc[m][n] = (f32x4){0.f,0.f,0.f,0.f};
  for (int u = 0; u < 16; ++u){
    int b = u & 1;
    asm volatile("s_waitcnt vmcnt(0)" ::: "memory");
    __syncthreads();
    int un = u + 1;
    f16x8 hv[4];
    if (un < 16){
      int b2 = un & 1;
      long long aoff = (long long)(un & 7) * 128;
      long long boff = aoff + ((un >> 3) ? edelt : 0);
      #pragma unroll
      for (int i = 0; i < 4; ++i)
        load_lds16(srcB[i] + boff, sm + BBUF + b2*16384 + i*4096 + ldst);
      const float* xr = xrow + (un & 7)*64;
      #pragma unroll
      for (int q2 = 0; q2 < 4; ++q2){
        float fv[8];
        *(float4*)&fv[0] = *(const float4*)(xr + q2*8);
        *(float4*)&fv[4] = *(const float4*)(xr + q2*8 + 4);
        hv[q2] = pack8f(fv);
      }
    }
    const char* Ab = sm + ABUF + b*16384;
    const char* Bb = sm + BBUF + b*16384;
    f16x8 af2[4][2], bf2[4][2];
    #pragma unroll
    for (int m=0;m<4;++m){
      int r = wm*64 + m*16 + (lane & 15);
      af2[m][0] = readF64h(Ab, r, (lane >> 4));
      af2[m][1] = readF64h(Ab, r, 4 + (lane >> 4));
    }
    #pragma unroll
    for (int n=0;n<4;++n){
      int r = wn*64 + n*16 + (lane & 15);
      bf2[n][0] = readF64h(Bb, r, (lane >> 4));
      bf2[n][1] = readF64h(Bb, r, 4 + (lane >> 4));
    }
    #pragma unroll
    for (int m=0;m<4;++m)
      #pragma unroll
      for (int n=0;n<4;++n){
        acc[m][n] = MFMAH(af2[m][0], bf2[n][0], acc[m][n]);
        acc[m][n] = MFMAH(af2[m][1], bf2[n][1], acc[m][n]);
      }
    if (un < 16){
      int b2 = un & 1;
      #pragma unroll
      for (int q2 = 0; q2 < 4; ++q2){
        int g = ach*4 + q2;
        *(f16x8*)(sm + ABUF + b2*16384 + arow*128 + ((g ^ (arow & 7)) << 4)) = hv[q2];
      }
    }
    if (u == 7){
      const float* bev = be + (size_t)eA*DDIM + nt*128;
      float bcol[4];
      #pragma unroll
      for (int n=0;n<4;++n) bcol[n] = bev[wn*64 + n*16 + (lane & 15)];
      #pragma unroll
      for (int m=0;m<4;++m)
        #pragma unroll
        for (int j=0;j<4;++j){
          int row = wm*64 + m*16 + ((lane >> 4) << 2) + j;
          float g = ((const float2*)(sm + LGOFF))[row].x;
          #pragma unroll
          for (int n=0;n<4;++n){
            res[m][n][j] = g * (acc[m][n][j] + bcol[n]);
            acc[m][n][j] = 0.f;
          }
        }
    }
    if (u == 15){
      const float* bev = be + (size_t)eB*DDIM + nt*128;
      float bcol[4];
      #pragma unroll
      for (int n=0;n<4;++n) bcol[n] = bev[wn*64 + n*16 + (lane & 15)];
      #pragma unroll
      for (int m=0;m<4;++m)
        #pragma unroll
        for (int j=0;j<4;++j){
          int row = wm*64 + m*16 + ((lane >> 4) << 2) + j;
          int tk = ((const int*)(sm + LTOK))[row];
          float g = ((const float2*)(sm + LGOFF))[row].y;
          if (tk >= 0){
            float* orow = out + (size_t)tk*DDIM + nt*128;
            #pragma unroll
            for (int n=0;n<4;++n)
              orow[wn*64 + n*16 + (lane & 15)] = res[m][n][j] + g * (acc[m][n][j] + bcol[n]);
          }
        }
    }
  }
}

// ---- host launch --------------------------------------------------------------
extern "C" void kernel_launch(void* const* d_in, const int* in_sizes, int n_in,
                              void* d_out, int out_size, void* d_ws, size_t ws_size,
                              hipStream_t stream)
{
  const float* x   = (const float*)d_in[0];
  const float* Wg1 = (const float*)d_in[1];
  const float* bg1 = (const float*)d_in[2];
  const float* Wg2 = (const float*)d_in[3];
  const float* bg2 = (const float*)d_in[4];
  const float* We  = (const float*)d_in[5];
  const float* be  = (const float*)d_in[6];
  float* out = (float*)d_out;
  char* ws = (char*)d_ws;

  f16*  Wt          = (f16*)(ws + 0);             // 8,388,608
  f16*  W1          = (f16*)(ws + 8388608);       //   131,072
  char* Wg2f        = ws + 8519680;               //     4,096
  char* CTRL        = ws + 8650752;               //     8,192
  int*  refine_cnt  = (int*)(CTRL);
  int*  ntiles      = (int*)(CTRL + 4);
  int*  counts      = (int*)(CTRL + 64);          // 256 ints
  int*  cursors     = (int*)(CTRL + 2048);        // 256 ints
  int*  bases       = (int*)(CTRL + 4096);        // 257 ints
  int2*   gate_e    = (int2*)(ws + 8658944);      // 1,048,576
  float2* gate_g    = (float2*)(ws + 9707520);    // 1,048,576
  int*  refine_list = (int*)(ws + 10756096);      //   524,288
  int*  pair_tok    = (int*)(ws + 11280384);      //   524,288
  float2* pair_g    = (float2*)(ws + 11804672);   // 1,048,576
  int*  tile_pair   = (int*)(ws + 12853248);      //    10,240
  int*  tile_row0   = (int*)(ws + 12863488);      //    10,240
  const size_t XBF_OFF = 16777216ull;
  const size_t XBF_BYTES = (size_t)NTOK * DDIM * 2;   // 134 MB (f16 x)
  bool bf16a = ws_size >= XBF_OFF + XBF_BYTES;
  f16* xbf = bf16a ? (f16*)(ws + XBF_OFF) : nullptr;

  hipLaunchKernelGGL(kconv,    dim3(17),   dim3(256), 0, stream, Wg1, Wg2, W1, Wg2f,
                     (int*)CTRL);
  hipLaunchKernelGGL(kgate,    dim3(1024), dim3(256), 0, stream, x, W1, Wg2f, bg1, bg2,
                     We, Wt, xbf, gate_e, gate_g, refine_cnt, refine_list, counts);
  hipLaunchKernelGGL(krefine,  dim3(1024), dim3(128), 0, stream, x, Wg1, bg1, Wg2, bg2,
                     refine_cnt, refine_list, gate_e, gate_g, counts);
  hipLaunchKernelGGL(kscatter, dim3(512),  dim3(256), 0, stream, gate_e, gate_g, counts,
                     bases, cursors, tile_pair, tile_row0, ntiles, pair_tok, pair_g,
                     bf16a ? 256 : 128);
  if (bf16a)
    hipLaunchKernelGGL(kexpert4, dim3(2816), dim3(512), 0, stream, xbf, Wt, be, out,
                       counts, bases, tile_pair, tile_row0, ntiles, pair_tok, pair_g);
  else
    hipLaunchKernelGGL(kexpertF, dim3(5120), dim3(256), 0, stream, x, Wt, be, out,
                       counts, bases, tile_pair, tile_row0, ntiles, pair_tok, pair_g);
  (void)in_sizes; (void)n_in; (void)out_size; (void)ws_size;
}